// Round 1
// baseline (289.349 us; speedup 1.0000x reference)
//
#include <hip/hip_runtime.h>
#include <math.h>

// ActionEmbedding: h = a[:, :3] @ pos_W + pos_b + sincos(euler(quat)) @ rot_W
//                      + rot_b + open_emb[idx];  out = LayerNorm(h) * g + b
// B = 65536 rows, H = 1024 cols, all fp32.
// Memory-bound: 256 MB out write + ~2 MB in. Design: weights pinned in VGPRs
// (4 cols/thread x 14 floats), 32 rows/block to amortize, sincos-of-euler
// computed algebraically (no transcendentals), one barrier per row.

#define HDIM 1024
#define TPB  256
#define CPT  4    // HDIM / TPB columns per thread
#define RPB  32   // rows per block

__global__ __launch_bounds__(TPB) void action_embed_kernel(
    const float* __restrict__ actions,
    const float* __restrict__ pos_W, const float* __restrict__ pos_b,
    const float* __restrict__ rot_W, const float* __restrict__ rot_b,
    const float* __restrict__ open_emb,
    const float* __restrict__ ln_g, const float* __restrict__ ln_b,
    float* __restrict__ out, int B)
{
    __shared__ float s_coef[RPB][12];     // c0..c2, sr,sp,sy, cr,cp,cy, openflag
    __shared__ float s_red[2][4][2];      // [buf][wave][sum, sumsq]

    const int tid  = threadIdx.x;
    const int col  = tid * CPT;
    const int row0 = blockIdx.x * RPB;

    // ---- weights for this thread's 4 columns -> registers (once per block) ----
    const float4 wp0 = *(const float4*)(pos_W + 0 * HDIM + col);
    const float4 wp1 = *(const float4*)(pos_W + 1 * HDIM + col);
    const float4 wp2 = *(const float4*)(pos_W + 2 * HDIM + col);
    const float4 wr0 = *(const float4*)(rot_W + 0 * HDIM + col);
    const float4 wr1 = *(const float4*)(rot_W + 1 * HDIM + col);
    const float4 wr2 = *(const float4*)(rot_W + 2 * HDIM + col);
    const float4 wr3 = *(const float4*)(rot_W + 3 * HDIM + col);
    const float4 wr4 = *(const float4*)(rot_W + 4 * HDIM + col);
    const float4 wr5 = *(const float4*)(rot_W + 5 * HDIM + col);
    const float4 wo0 = *(const float4*)(open_emb + 0 * HDIM + col);
    const float4 wo1 = *(const float4*)(open_emb + 1 * HDIM + col);
    float4 bb;
    {
        float4 pb = *(const float4*)(pos_b + col);
        float4 rb = *(const float4*)(rot_b + col);
        bb = make_float4(pb.x + rb.x, pb.y + rb.y, pb.z + rb.z, pb.w + rb.w);
    }
    const float4 g  = *(const float4*)(ln_g + col);
    const float4 bt = *(const float4*)(ln_b + col);

    // ---- per-row scalar coefficients (threads 0..RPB-1, one row each) ----
    if (tid < RPB) {
        const int r = row0 + tid;
        if (r < B) {
            const float4 a0 = *(const float4*)(actions + (size_t)r * 8);
            const float4 a1 = *(const float4*)(actions + (size_t)r * 8 + 4);
            float qx = a0.w, qy = a1.x, qz = a1.y, qw = a1.z;
            const float n = 1.0f / sqrtf(qx * qx + qy * qy + qz * qz + qw * qw);
            qx *= n; qy *= n; qz *= n; qw *= n;
            // roll = atan2(2(wx+yz), 1-2(x^2+y^2)) -> sin/cos without atan2
            const float sr_n = 2.0f * (qw * qx + qy * qz);
            const float cr_n = 1.0f - 2.0f * (qx * qx + qy * qy);
            float sr, cr;
            {
                const float r2 = sr_n * sr_n + cr_n * cr_n;
                if (r2 < 1e-37f) { sr = 0.0f; cr = 1.0f; }
                else { const float ri = 1.0f / sqrtf(r2); sr = sr_n * ri; cr = cr_n * ri; }
            }
            // pitch = asin(clamp(2(wy-zx))) -> sin = arg, cos = sqrt(1-arg^2)
            float sp = 2.0f * (qw * qy - qz * qx);
            sp = fminf(1.0f, fmaxf(-1.0f, sp));
            const float cp = sqrtf(fmaxf(0.0f, 1.0f - sp * sp));
            // yaw = atan2(2(wz+xy), 1-2(y^2+z^2))
            const float sy_n = 2.0f * (qw * qz + qx * qy);
            const float cy_n = 1.0f - 2.0f * (qy * qy + qz * qz);
            float sy, cy;
            {
                const float r2 = sy_n * sy_n + cy_n * cy_n;
                if (r2 < 1e-37f) { sy = 0.0f; cy = 1.0f; }
                else { const float ri = 1.0f / sqrtf(r2); sy = sy_n * ri; cy = cy_n * ri; }
            }
            s_coef[tid][0] = a0.x;  // pos x
            s_coef[tid][1] = a0.y;  // pos y
            s_coef[tid][2] = a0.z;  // pos z
            s_coef[tid][3] = sr;
            s_coef[tid][4] = sp;
            s_coef[tid][5] = sy;
            s_coef[tid][6] = cr;
            s_coef[tid][7] = cp;
            s_coef[tid][8] = cy;
            int idx = (int)a1.w;                 // astype(int32) truncation
            idx = idx < 0 ? 0 : (idx > 1 ? 1 : idx);
            s_coef[tid][9] = (float)idx;
        }
    }
    __syncthreads();

    const int wave = tid >> 6;
    const int lane = tid & 63;
    const int nrows = (B - row0 < RPB) ? (B - row0) : RPB;

    for (int rr = 0; rr < nrows; ++rr) {
        const float c0 = s_coef[rr][0], c1 = s_coef[rr][1], c2 = s_coef[rr][2];
        const float sr = s_coef[rr][3], sp = s_coef[rr][4], sy = s_coef[rr][5];
        const float cr = s_coef[rr][6], cp = s_coef[rr][7], cy = s_coef[rr][8];
        const bool open = s_coef[rr][9] != 0.0f;

        float4 h;
#define COMPONENT(f)                                                        \
        {                                                                   \
            float hh = bb.f + (open ? wo1.f : wo0.f);                       \
            hh = fmaf(c0, wp0.f, hh);                                       \
            hh = fmaf(c1, wp1.f, hh);                                       \
            hh = fmaf(c2, wp2.f, hh);                                       \
            hh = fmaf(sr, wr0.f, hh);                                       \
            hh = fmaf(sp, wr1.f, hh);                                       \
            hh = fmaf(sy, wr2.f, hh);                                       \
            hh = fmaf(cr, wr3.f, hh);                                       \
            hh = fmaf(cp, wr4.f, hh);                                       \
            hh = fmaf(cy, wr5.f, hh);                                       \
            h.f = hh;                                                       \
        }
        COMPONENT(x) COMPONENT(y) COMPONENT(z) COMPONENT(w)
#undef COMPONENT

        // block-wide sum / sumsq over HDIM
        float ps = h.x + h.y + h.z + h.w;
        float pq = h.x * h.x + h.y * h.y + h.z * h.z + h.w * h.w;
        #pragma unroll
        for (int off = 32; off > 0; off >>= 1) {
            ps += __shfl_xor(ps, off, 64);
            pq += __shfl_xor(pq, off, 64);
        }
        const int buf = rr & 1;
        if (lane == 0) {
            s_red[buf][wave][0] = ps;
            s_red[buf][wave][1] = pq;
        }
        __syncthreads();
        const float sum = s_red[buf][0][0] + s_red[buf][1][0] +
                          s_red[buf][2][0] + s_red[buf][3][0];
        const float sq  = s_red[buf][0][1] + s_red[buf][1][1] +
                          s_red[buf][2][1] + s_red[buf][3][1];

        const float mu  = sum * (1.0f / HDIM);
        float var = fmaf(sq, 1.0f / HDIM, -mu * mu);
        var = fmaxf(var, 0.0f);
        const float rstd = 1.0f / sqrtf(var + 1e-12f);

        float4 o;
        o.x = fmaf((h.x - mu) * rstd, g.x, bt.x);
        o.y = fmaf((h.y - mu) * rstd, g.y, bt.y);
        o.z = fmaf((h.z - mu) * rstd, g.z, bt.z);
        o.w = fmaf((h.w - mu) * rstd, g.w, bt.w);
        *(float4*)(out + (size_t)(row0 + rr) * HDIM + col) = o;
        // no trailing barrier: s_red is double-buffered (buf = rr & 1), and the
        // next iteration's barrier orders reads-of-buf before writes-of-buf+2
    }
}

extern "C" void kernel_launch(void* const* d_in, const int* in_sizes, int n_in,
                              void* d_out, int out_size, void* d_ws, size_t ws_size,
                              hipStream_t stream) {
    const float* actions  = (const float*)d_in[0];
    const float* pos_W    = (const float*)d_in[1];
    const float* pos_b    = (const float*)d_in[2];
    const float* rot_W    = (const float*)d_in[3];
    const float* rot_b    = (const float*)d_in[4];
    const float* open_emb = (const float*)d_in[5];
    const float* ln_g     = (const float*)d_in[6];
    const float* ln_b     = (const float*)d_in[7];
    float* out = (float*)d_out;

    const int B = in_sizes[0] / 8;
    const int grid = (B + RPB - 1) / RPB;
    hipLaunchKernelGGL(action_embed_kernel, dim3(grid), dim3(TPB), 0, stream,
                       actions, pos_W, pos_b, rot_W, rot_b, open_emb,
                       ln_g, ln_b, out, B);
}